// Round 5
// baseline (385.123 us; speedup 1.0000x reference)
//
#include <hip/hip_runtime.h>

typedef __attribute__((ext_vector_type(4))) float f32x4;
typedef __attribute__((ext_vector_type(8))) short bf16x8;
typedef unsigned short u16;
typedef unsigned int u32;

// Problem constants
// x: (32,128,64,64) f32; gamma,beta: (128,) f32; weight: (1152,256) f32
// out: (32,256,62,62) f32
// h' (ws): NHWC bf16, element (b*4096 + s)*128 + c, 16,777,216 elems (+pad)
// Wt (ws): [256][1152] bf16, k' = (kh*3+kw)*128 + c
// stats (ws): [128][2] f32 (sum, sumsq)

__device__ __forceinline__ u16 f2bf(float f) {
  union { float f; u32 u; } v; v.f = f;
  u32 r = v.u + 0x7fffu + ((v.u >> 16) & 1u);
  return (u16)(r >> 16);
}

__device__ __forceinline__ void async16(u16* lds, const u16* g) {
  __builtin_amdgcn_global_load_lds((const __attribute__((address_space(1))) u32*)g,
                                   (__attribute__((address_space(3))) u32*)lds, 16, 0, 0);
}

// ---------------- kernel 1: per-channel sum / sumsq ----------------
__global__ __launch_bounds__(256) void stats_kernel(const float* __restrict__ x,
                                                    float* __restrict__ stats) {
  int plane = blockIdx.x;          // b*128 + c
  int c = plane & 127;
  const float4* p = (const float4*)(x + (size_t)plane * 4096);
  int t = threadIdx.x;
  float s = 0.f, sq = 0.f;
#pragma unroll
  for (int i = 0; i < 4; i++) {
    float4 v = p[t + i * 256];
    s  += v.x + v.y + v.z + v.w;
    sq += v.x * v.x + v.y * v.y + v.z * v.z + v.w * v.w;
  }
#pragma unroll
  for (int off = 32; off; off >>= 1) {
    s  += __shfl_down(s, off);
    sq += __shfl_down(sq, off);
  }
  __shared__ float red[8];
  int w = t >> 6;
  if ((t & 63) == 0) { red[w * 2] = s; red[w * 2 + 1] = sq; }
  __syncthreads();
  if (t == 0) {
    s  = red[0] + red[2] + red[4] + red[6];
    sq = red[1] + red[3] + red[5] + red[7];
    atomicAdd(&stats[c * 2], s);
    atomicAdd(&stats[c * 2 + 1], sq);
  }
}

// ---------------- kernel 2: normalize + relu + NCHW->NHWC bf16 ----------------
__global__ __launch_bounds__(256) void norm_kernel(const float* __restrict__ x,
                                                   const float* __restrict__ gamma,
                                                   const float* __restrict__ beta,
                                                   const float* __restrict__ stats,
                                                   u16* __restrict__ hp) {
  int bid = blockIdx.x;            // b(32) * ct(2) * st(64)
  int b  = bid >> 7;
  int ct = (bid >> 6) & 1;
  int st = bid & 63;
  int cb = ct * 64, sb = st * 64;
  __shared__ __align__(16) u16 tile[64 * 64];   // swizzled [c][s] bf16
  char* tb = (char*)tile;
  int t  = threadIdx.x;
  int cl = t >> 2;                 // 0..63 channel-local
  int sc = (t & 3) * 16;           // s offset
  int c  = cb + cl;
  const float inv_n = 1.0f / 131072.0f;
  float sum = stats[c * 2], sumsq = stats[c * 2 + 1];
  float mean = sum * inv_n;
  float var  = sumsq * inv_n - mean * mean;
  float rstd = rsqrtf(var + 1e-5f);
  float a  = gamma[c] * rstd;
  float bb = beta[c] - mean * a;
  const float* src = x + (size_t)(b * 128 + c) * 4096 + sb + sc;
  __align__(16) u16 vals[16];
#pragma unroll
  for (int i = 0; i < 4; i++) {
    float4 v = ((const float4*)src)[i];
    vals[i * 4 + 0] = f2bf(fmaxf(v.x * a + bb, 0.f));
    vals[i * 4 + 1] = f2bf(fmaxf(v.y * a + bb, 0.f));
    vals[i * 4 + 2] = f2bf(fmaxf(v.z * a + bb, 0.f));
    vals[i * 4 + 3] = f2bf(fmaxf(v.w * a + bb, 0.f));
  }
  int swz = (cl ^ (cl >> 4)) & 7;
#pragma unroll
  for (int u = 0; u < 2; u++) {
    int byte_off = cl * 128 + ((((sc + u * 8)) * 2) ^ (swz << 4));
    *(uint4*)(tb + byte_off) = ((const uint4*)vals)[u];
  }
  __syncthreads();
  int sl = t >> 2;                 // pixel-local 0..63
  int cc = (t & 3) * 16;
  __align__(16) u16 ov[16];
#pragma unroll
  for (int j = 0; j < 16; j++) {
    int cr = cc + j;
    int sw = (cr ^ (cr >> 4)) & 7;
    ov[j] = *(const u16*)(tb + cr * 128 + ((sl * 2) ^ (sw << 4)));
  }
  u16* dst = hp + ((size_t)(b * 4096) + sb + sl) * 128 + cb + cc;
  ((uint4*)dst)[0] = ((const uint4*)ov)[0];
  ((uint4*)dst)[1] = ((const uint4*)ov)[1];
}

// ---------------- kernel 3: weight reorder -> Wt[n][(kh*3+kw)*128+c] bf16 ----
__global__ __launch_bounds__(128) void wt_kernel(const float* __restrict__ w,
                                                 u16* __restrict__ wt) {
  int seg = blockIdx.x;            // 0..8 = kh*3+kw
  int n   = blockIdx.y;            // 0..255
  int c   = threadIdx.x;           // 0..127
  float v = w[(size_t)(c * 9 + seg) * 256 + n];
  wt[(size_t)n * 1152 + seg * 128 + c] = f2bf(v);
}

// ---------------- kernel 4: implicit-GEMM conv + residual ----------------
// C[m][n]: m = (b, s) pixel (s in [0,3968), padded W=64), n = out channel.
// D[n-rows][m-cols] via mfma(Wt-frag, h-frag, acc) so stores coalesce over ow.
__global__ __launch_bounds__(256) void conv_kernel(const u16* __restrict__ hp,
                                                   const u16* __restrict__ wt,
                                                   const float* __restrict__ x,
                                                   float* __restrict__ out) {
  __shared__ __align__(16) u16 Al[128 * 64];   // h tile [m][k] swizzled
  __shared__ __align__(16) u16 Bl[128 * 64];   // W tile [n][k] swizzled
  int bid = blockIdx.x;
  int nt = bid & 1, mt = bid >> 1;
  int b  = mt / 31;
  int st = mt - b * 31;
  int sbase = st * 128;
  size_t pixbase = (size_t)b * 4096 + sbase;
  int tid = threadIdx.x, wid = tid >> 6, lane = tid & 63;
  int wm = wid >> 1, wn = wid & 1;

  f32x4 zero = {0.f, 0.f, 0.f, 0.f};
  f32x4 acc[4][4];
#pragma unroll
  for (int ni = 0; ni < 4; ni++)
#pragma unroll
    for (int mi = 0; mi < 4; mi++) acc[ni][mi] = zero;

  int l3 = lane >> 3, l7 = lane & 7;
  int c8x = l7 ^ l3;                       // pre-swizzled source chunk
  int laneA = l3 * 128 + c8x * 8;          // elements within 8-row A block
  int laneB = l3 * 1152 + c8x * 8;         // elements within 8-row B block
  const u16* wtbase = wt + (size_t)(nt * 128) * 1152;
  int xo = l7 << 4;                        // fragment-read XOR term

  for (int kt = 0; kt < 18; ++kt) {
    int seg = kt >> 1;
    int chalf = (kt & 1) * 64;
    int dpix = (seg / 3) * 64 + (seg % 3);
    const u16* gA = hp + (pixbase + dpix) * 128 + chalf + laneA;
    const u16* gB = wtbase + seg * 128 + chalf + laneB;
    __syncthreads();
#pragma unroll
    for (int i = 0; i < 4; i++) {
      int rb = wid * 32 + i * 8;
      async16(&Al[rb * 64], gA + rb * 128);
      async16(&Bl[rb * 64], gB + (size_t)rb * 1152);
    }
    __syncthreads();
    const char* Ab = (const char*)Al;
    const char* Bb = (const char*)Bl;
#pragma unroll
    for (int kk = 0; kk < 2; kk++) {
      int ko = kk * 64 + ((lane >> 4) * 16);
      bf16x8 af[4], hf[4];
#pragma unroll
      for (int ni = 0; ni < 4; ni++) {
        int row = wn * 64 + ni * 16 + (lane & 15);
        af[ni] = *(const bf16x8*)(Bb + row * 128 + (ko ^ xo));
      }
#pragma unroll
      for (int mi = 0; mi < 4; mi++) {
        int row = wm * 64 + mi * 16 + (lane & 15);
        hf[mi] = *(const bf16x8*)(Ab + row * 128 + (ko ^ xo));
      }
#pragma unroll
      for (int ni = 0; ni < 4; ni++)
#pragma unroll
        for (int mi = 0; mi < 4; mi++)
          acc[ni][mi] = __builtin_amdgcn_mfma_f32_16x16x32_bf16(af[ni], hf[mi], acc[ni][mi], 0, 0, 0);
    }
  }

  // epilogue: D row = n-local quad, col = m; mask junk ow, add residual, store
  int nbase = nt * 128 + wn * 64 + ((lane >> 4) << 2);
  int l15 = lane & 15;
#pragma unroll
  for (int mi = 0; mi < 4; mi++) {
    int sl = sbase + wm * 64 + mi * 16 + l15;
    int ow = sl & 63, oh = sl >> 6;
    if (ow >= 62) continue;
#pragma unroll
    for (int ni = 0; ni < 4; ni++) {
      int n0 = nbase + ni * 16;
#pragma unroll
      for (int r = 0; r < 4; r++) {
        int n = n0 + r;
        float v = acc[ni][mi][r];
        if (n < 128) v += x[(size_t)(b * 128 + n) * 4096 + (oh + 1) * 64 + ow + 1];
        out[((size_t)(b * 256 + n) * 62 + oh) * 62 + ow] = v;
      }
    }
  }
}

extern "C" void kernel_launch(void* const* d_in, const int* in_sizes, int n_in,
                              void* d_out, int out_size, void* d_ws, size_t ws_size,
                              hipStream_t stream) {
  const float* x     = (const float*)d_in[0];
  const float* gamma = (const float*)d_in[1];
  const float* beta  = (const float*)d_in[2];
  const float* w     = (const float*)d_in[3];
  float* out = (float*)d_out;
  char* ws = (char*)d_ws;

  const size_t HP_BYTES = (size_t)16777216 * 2 + 4096;  // h' + overrun pad
  u16* hp   = (u16*)ws;
  u16* wt   = (u16*)(ws + HP_BYTES);
  float* stats = (float*)(ws + HP_BYTES + 589824);

  hipMemsetAsync(stats, 0, 256 * sizeof(float), stream);
  hipLaunchKernelGGL(stats_kernel, dim3(4096), dim3(256), 0, stream, x, stats);
  hipLaunchKernelGGL(wt_kernel, dim3(9, 256), dim3(128), 0, stream, w, wt);
  hipLaunchKernelGGL(norm_kernel, dim3(4096), dim3(256), 0, stream, x, gamma, beta, stats, hp);
  hipLaunchKernelGGL(conv_kernel, dim3(992 * 2), dim3(256), 0, stream, hp, wt, x, out);
}

// Round 7
// 381.945 us; speedup vs baseline: 1.0083x; 1.0083x over previous
//
#include <hip/hip_runtime.h>

typedef __attribute__((ext_vector_type(4))) float f32x4;
typedef __attribute__((ext_vector_type(8))) short bf16x8;
typedef unsigned short u16;
typedef unsigned int u32;

// x: (32,128,64,64) f32; gamma,beta: (128,) f32; weight: (1152,256) f32
// out: (32,256,62,62) f32
// hp (ws): NHWC bf16, element (b*4096 + s)*128 + c
// wt (ws): [256][1152] bf16, k' = (kh*3+kw)*128 + c
// part (ws): [128][4][2] f32 partial (sum, sumsq), no atomics/memset needed

__device__ __forceinline__ u16 f2bf(float f) {
  union { float f; u32 u; } v; v.f = f;
  u32 r = v.u + 0x7fffu + ((v.u >> 16) & 1u);
  return (u16)(r >> 16);
}

__device__ __forceinline__ void async16(u16* lds, const u16* g) {
  __builtin_amdgcn_global_load_lds((const __attribute__((address_space(1))) u32*)g,
                                   (__attribute__((address_space(3))) u32*)lds, 16, 0, 0);
}

// ------- kernel 1: per-channel partial stats (no atomics) + weight reorder ----
__global__ __launch_bounds__(256) void statswt_kernel(const float* __restrict__ x,
                                                      const float* __restrict__ w,
                                                      float* __restrict__ part,
                                                      u16* __restrict__ wt) {
  int bid = blockIdx.x;            // 512 = c(128) * q(4)
  int c = bid >> 2, q = bid & 3;
  int t = threadIdx.x;
  float s = 0.f, sq = 0.f;
  for (int pb = 0; pb < 8; pb++) {
    int b = q * 8 + pb;
    const float4* p = (const float4*)(x + (size_t)(b * 128 + c) * 4096);
#pragma unroll
    for (int i = 0; i < 4; i++) {
      float4 v = p[t + i * 256];
      s  += v.x + v.y + v.z + v.w;
      sq += v.x * v.x + v.y * v.y + v.z * v.z + v.w * v.w;
    }
  }
#pragma unroll
  for (int off = 32; off; off >>= 1) {
    s  += __shfl_down(s, off);
    sq += __shfl_down(sq, off);
  }
  __shared__ float red[8];
  int wv = t >> 6;
  if ((t & 63) == 0) { red[wv * 2] = s; red[wv * 2 + 1] = sq; }
  __syncthreads();
  if (t == 0) {
    part[c * 8 + q * 2]     = red[0] + red[2] + red[4] + red[6];
    part[c * 8 + q * 2 + 1] = red[1] + red[3] + red[5] + red[7];
  }
  // weight reorder slice: flat d = (seg*256+n)*128 + cw, 512*576 = 294912 total
  for (int idx = bid * 576 + t; idx < bid * 576 + 576; idx += 256) {
    int cw = idx & 127, sn = idx >> 7;
    int seg = sn >> 8, n = sn & 255;
    wt[(size_t)n * 1152 + seg * 128 + cw] = f2bf(w[(size_t)(cw * 9 + seg) * 256 + n]);
  }
}

// ---------------- kernel 2: normalize + relu + NCHW->NHWC bf16 ----------------
__global__ __launch_bounds__(256) void norm_kernel(const float* __restrict__ x,
                                                   const float* __restrict__ gamma,
                                                   const float* __restrict__ beta,
                                                   const float* __restrict__ part,
                                                   u16* __restrict__ hp) {
  int bid = blockIdx.x;            // b(32) * ct(2) * st(64)
  int b  = bid >> 7;
  int ct = (bid >> 6) & 1;
  int st = bid & 63;
  int cb = ct * 64, sb = st * 64;
  __shared__ __align__(16) u16 tile[64 * 64];   // swizzled [c][s] bf16
  char* tb = (char*)tile;
  int t  = threadIdx.x;
  int cl = t >> 2;                 // 0..63 channel-local
  int sc = (t & 3) * 16;           // s offset
  int c  = cb + cl;
  const float inv_n = 1.0f / 131072.0f;
  float sum   = part[c * 8 + 0] + part[c * 8 + 2] + part[c * 8 + 4] + part[c * 8 + 6];
  float sumsq = part[c * 8 + 1] + part[c * 8 + 3] + part[c * 8 + 5] + part[c * 8 + 7];
  float mean = sum * inv_n;
  float var  = sumsq * inv_n - mean * mean;
  float rstd = rsqrtf(var + 1e-5f);
  float a  = gamma[c] * rstd;
  float bb = beta[c] - mean * a;
  const float* src = x + (size_t)(b * 128 + c) * 4096 + sb + sc;
  __align__(16) u16 vals[16];
#pragma unroll
  for (int i = 0; i < 4; i++) {
    float4 v = ((const float4*)src)[i];
    vals[i * 4 + 0] = f2bf(fmaxf(v.x * a + bb, 0.f));
    vals[i * 4 + 1] = f2bf(fmaxf(v.y * a + bb, 0.f));
    vals[i * 4 + 2] = f2bf(fmaxf(v.z * a + bb, 0.f));
    vals[i * 4 + 3] = f2bf(fmaxf(v.w * a + bb, 0.f));
  }
  int swz = (cl ^ (cl >> 4)) & 7;
#pragma unroll
  for (int u = 0; u < 2; u++) {
    int byte_off = cl * 128 + ((((sc + u * 8)) * 2) ^ (swz << 4));
    *(uint4*)(tb + byte_off) = ((const uint4*)vals)[u];
  }
  __syncthreads();
  int sl = t >> 2;                 // pixel-local 0..63
  int cc = (t & 3) * 16;
  __align__(16) u16 ov[16];
#pragma unroll
  for (int j = 0; j < 16; j++) {
    int cr = cc + j;
    int sw = (cr ^ (cr >> 4)) & 7;
    ov[j] = *(const u16*)(tb + cr * 128 + ((sl * 2) ^ (sw << 4)));
  }
  u16* dst = hp + ((size_t)(b * 4096) + sb + sl) * 128 + cb + cc;
  ((uint4*)dst)[0] = ((const uint4*)ov)[0];
  ((uint4*)dst)[1] = ((const uint4*)ov)[1];
}

// ---------------- kernel 3: implicit-GEMM conv + residual (dbuf prefetch) ----
__global__ __launch_bounds__(256) void conv_kernel(const u16* __restrict__ hp,
                                                   const u16* __restrict__ wt,
                                                   const float* __restrict__ x,
                                                   float* __restrict__ out) {
  __shared__ __align__(16) u16 Al[2][128 * 64];   // h tile [m][k] swizzled
  __shared__ __align__(16) u16 Bl[2][128 * 64];   // W tile [n][k] swizzled
  int bid = blockIdx.x;
  int nt = bid & 1, mt = bid >> 1;
  int b  = mt / 31;
  int st = mt - b * 31;
  int sbase = st * 128;
  size_t pixbase = (size_t)b * 4096 + sbase;
  int tid = threadIdx.x, wid = tid >> 6, lane = tid & 63;
  int wm = wid >> 1, wn = wid & 1;

  f32x4 zero = {0.f, 0.f, 0.f, 0.f};
  f32x4 acc[4][4];
#pragma unroll
  for (int ni = 0; ni < 4; ni++)
#pragma unroll
    for (int mi = 0; mi < 4; mi++) acc[ni][mi] = zero;

  int l3 = lane >> 3, l7 = lane & 7;
  int c8x = l7 ^ l3;                       // pre-swizzled source chunk
  int laneA = l3 * 128 + c8x * 8;
  int laneB = l3 * 1152 + c8x * 8;
  const u16* wtbase = wt + (size_t)(nt * 128) * 1152;
  int xo = l7 << 4;                        // fragment-read XOR term

  auto stage = [&](int buf, int kt) {
    int seg = kt >> 1;
    int chalf = (kt & 1) * 64;
    int dpix = (seg / 3) * 64 + (seg % 3);
    const u16* gA = hp + (pixbase + dpix) * 128 + chalf + laneA;
    const u16* gB = wtbase + seg * 128 + chalf + laneB;
#pragma unroll
    for (int i = 0; i < 4; i++) {
      int rb = wid * 32 + i * 8;
      async16(&Al[buf][rb * 64], gA + rb * 128);
      async16(&Bl[buf][rb * 64], gB + (size_t)rb * 1152);
    }
  };

  stage(0, 0);
  asm volatile("s_waitcnt vmcnt(0)" ::: "memory");
  __builtin_amdgcn_s_barrier();

  int cur = 0;
  for (int kt = 0; kt < 18; ++kt) {
    if (kt + 1 < 18) stage(cur ^ 1, kt + 1);   // prefetch next tile
    const char* Ab = (const char*)Al[cur];
    const char* Bb = (const char*)Bl[cur];
#pragma unroll
    for (int kk = 0; kk < 2; kk++) {
      int ko = kk * 64 + ((lane >> 4) * 16);
      bf16x8 af[4], hf[4];
#pragma unroll
      for (int ni = 0; ni < 4; ni++) {
        int row = wn * 64 + ni * 16 + (lane & 15);
        af[ni] = *(const bf16x8*)(Bb + row * 128 + (ko ^ xo));
      }
#pragma unroll
      for (int mi = 0; mi < 4; mi++) {
        int row = wm * 64 + mi * 16 + (lane & 15);
        hf[mi] = *(const bf16x8*)(Ab + row * 128 + (ko ^ xo));
      }
#pragma unroll
      for (int ni = 0; ni < 4; ni++)
#pragma unroll
        for (int mi = 0; mi < 4; mi++)
          acc[ni][mi] = __builtin_amdgcn_mfma_f32_16x16x32_bf16(af[ni], hf[mi], acc[ni][mi], 0, 0, 0);
    }
    asm volatile("s_waitcnt vmcnt(0)" ::: "memory");  // prefetch landed
    __builtin_amdgcn_s_barrier();                     // all waves done reading cur
    cur ^= 1;
  }

  // epilogue: D row = n-local quad, col = m; mask junk ow, add residual, store
  int nbase = nt * 128 + wn * 64 + ((lane >> 4) << 2);
  int l15 = lane & 15;
#pragma unroll
  for (int mi = 0; mi < 4; mi++) {
    int sl = sbase + wm * 64 + mi * 16 + l15;
    int ow = sl & 63, oh = sl >> 6;
    if (ow >= 62) continue;
#pragma unroll
    for (int ni = 0; ni < 4; ni++) {
      int n0 = nbase + ni * 16;
#pragma unroll
      for (int r = 0; r < 4; r++) {
        int n = n0 + r;
        float v = acc[ni][mi][r];
        if (n < 128) v += x[(size_t)(b * 128 + n) * 4096 + (oh + 1) * 64 + ow + 1];
        out[((size_t)(b * 256 + n) * 62 + oh) * 62 + ow] = v;
      }
    }
  }
}

extern "C" void kernel_launch(void* const* d_in, const int* in_sizes, int n_in,
                              void* d_out, int out_size, void* d_ws, size_t ws_size,
                              hipStream_t stream) {
  const float* x     = (const float*)d_in[0];
  const float* gamma = (const float*)d_in[1];
  const float* beta  = (const float*)d_in[2];
  const float* w     = (const float*)d_in[3];
  float* out = (float*)d_out;
  char* ws = (char*)d_ws;

  const size_t HP_BYTES = (size_t)16777216 * 2 + 4096;  // hp + overrun pad
  u16* hp    = (u16*)ws;
  u16* wt    = (u16*)(ws + HP_BYTES);
  float* part = (float*)(ws + HP_BYTES + 589824);       // 128*4*2 floats

  hipLaunchKernelGGL(statswt_kernel, dim3(512), dim3(256), 0, stream, x, w, part, wt);
  hipLaunchKernelGGL(norm_kernel, dim3(4096), dim3(256), 0, stream, x, gamma, beta, part, hp);
  hipLaunchKernelGGL(conv_kernel, dim3(992 * 2), dim3(256), 0, stream, hp, wt, x, out);
}

// Round 11
// 341.251 us; speedup vs baseline: 1.1286x; 1.1193x over previous
//
#include <hip/hip_runtime.h>

typedef __attribute__((ext_vector_type(4))) float f32x4;
typedef __attribute__((ext_vector_type(8))) short bf16x8;
typedef unsigned short u16;
typedef unsigned int u32;

// x: (32,128,64,64) f32; gamma,beta: (128,) f32; weight: (1152,256) f32
// out: (32,256,62,62) f32
// hp (ws): NHWC bf16, element (b*4096 + s)*128 + c
// wt (ws): [256][1152] bf16, k' = (kh*3+kw)*128 + c
// part (ws): [128][4][2] f32 partial (sum, sumsq)

__device__ __forceinline__ u16 f2bf(float f) {
  union { float f; u32 u; } v; v.f = f;
  u32 r = v.u + 0x7fffu + ((v.u >> 16) & 1u);
  return (u16)(r >> 16);
}

__device__ __forceinline__ void async16(u16* lds, const u16* g) {
  __builtin_amdgcn_global_load_lds((const __attribute__((address_space(1))) u32*)g,
                                   (__attribute__((address_space(3))) u32*)lds, 16, 0, 0);
}

// ------- kernel 1: per-channel partial stats (no atomics) + weight reorder ----
__global__ __launch_bounds__(256) void statswt_kernel(const float* __restrict__ x,
                                                      const float* __restrict__ w,
                                                      float* __restrict__ part,
                                                      u16* __restrict__ wt) {
  int bid = blockIdx.x;            // 512 = c(128) * q(4)
  int c = bid >> 2, q = bid & 3;
  int t = threadIdx.x;
  float s = 0.f, sq = 0.f;
  for (int pb = 0; pb < 8; pb++) {
    int b = q * 8 + pb;
    const float4* p = (const float4*)(x + (size_t)(b * 128 + c) * 4096);
#pragma unroll
    for (int i = 0; i < 4; i++) {
      float4 v = p[t + i * 256];
      s  += v.x + v.y + v.z + v.w;
      sq += v.x * v.x + v.y * v.y + v.z * v.z + v.w * v.w;
    }
  }
#pragma unroll
  for (int off = 32; off; off >>= 1) {
    s  += __shfl_down(s, off);
    sq += __shfl_down(sq, off);
  }
  __shared__ float red[8];
  int wv = t >> 6;
  if ((t & 63) == 0) { red[wv * 2] = s; red[wv * 2 + 1] = sq; }
  __syncthreads();
  if (t == 0) {
    part[c * 8 + q * 2]     = red[0] + red[2] + red[4] + red[6];
    part[c * 8 + q * 2 + 1] = red[1] + red[3] + red[5] + red[7];
  }
  for (int idx = bid * 576 + t; idx < bid * 576 + 576; idx += 256) {
    int cw = idx & 127, sn = idx >> 7;
    int seg = sn >> 8, n = sn & 255;
    wt[(size_t)n * 1152 + seg * 128 + cw] = f2bf(w[(size_t)(cw * 9 + seg) * 256 + n]);
  }
}

// ---------------- kernel 2: normalize + relu + NCHW->NHWC bf16 ----------------
__global__ __launch_bounds__(256) void norm_kernel(const float* __restrict__ x,
                                                   const float* __restrict__ gamma,
                                                   const float* __restrict__ beta,
                                                   const float* __restrict__ part,
                                                   u16* __restrict__ hp) {
  int bid = blockIdx.x;            // b(32) * ct(2) * st(64)
  int b  = bid >> 7;
  int ct = (bid >> 6) & 1;
  int st = bid & 63;
  int cb = ct * 64, sb = st * 64;
  __shared__ __align__(16) u16 tile[64 * 64];
  char* tb = (char*)tile;
  int t  = threadIdx.x;
  int cl = t >> 2;
  int sc = (t & 3) * 16;
  int c  = cb + cl;
  const float inv_n = 1.0f / 131072.0f;
  float sum   = part[c * 8 + 0] + part[c * 8 + 2] + part[c * 8 + 4] + part[c * 8 + 6];
  float sumsq = part[c * 8 + 1] + part[c * 8 + 3] + part[c * 8 + 5] + part[c * 8 + 7];
  float mean = sum * inv_n;
  float var  = sumsq * inv_n - mean * mean;
  float rstd = rsqrtf(var + 1e-5f);
  float a  = gamma[c] * rstd;
  float bb = beta[c] - mean * a;
  const float* src = x + (size_t)(b * 128 + c) * 4096 + sb + sc;
  __align__(16) u16 vals[16];
#pragma unroll
  for (int i = 0; i < 4; i++) {
    float4 v = ((const float4*)src)[i];
    vals[i * 4 + 0] = f2bf(fmaxf(v.x * a + bb, 0.f));
    vals[i * 4 + 1] = f2bf(fmaxf(v.y * a + bb, 0.f));
    vals[i * 4 + 2] = f2bf(fmaxf(v.z * a + bb, 0.f));
    vals[i * 4 + 3] = f2bf(fmaxf(v.w * a + bb, 0.f));
  }
  int swz = (cl ^ (cl >> 4)) & 7;
#pragma unroll
  for (int u = 0; u < 2; u++) {
    int byte_off = cl * 128 + ((((sc + u * 8)) * 2) ^ (swz << 4));
    *(uint4*)(tb + byte_off) = ((const uint4*)vals)[u];
  }
  __syncthreads();
  int sl = t >> 2;
  int cc = (t & 3) * 16;
  __align__(16) u16 ov[16];
#pragma unroll
  for (int j = 0; j < 16; j++) {
    int cr = cc + j;
    int sw = (cr ^ (cr >> 4)) & 7;
    ov[j] = *(const u16*)(tb + cr * 128 + ((sl * 2) ^ (sw << 4)));
  }
  u16* dst = hp + ((size_t)(b * 4096) + sb + sl) * 128 + cb + cc;
  ((uint4*)dst)[0] = ((const uint4*)ov)[0];
  ((uint4*)dst)[1] = ((const uint4*)ov)[1];
}

// -------- kernel 3: implicit-GEMM conv + residual (3-buf, counted vmcnt) -----
// BM=128 pixels, BN=256 (all out-channels), BK=64. 8 waves: wm(2) x wn(4).
// Pipeline 2-deep: tile kt staged at iter kt-2; main-loop wait = vmcnt(6).
__global__ __launch_bounds__(512, 2) void conv_kernel(const u16* __restrict__ hp,
                                                      const u16* __restrict__ wt,
                                                      const float* __restrict__ x,
                                                      float* __restrict__ out) {
  // per buf (24576 u16 = 48KB): A[128][64] @ 0, B[256][64] @ 8192 (u16 units)
  __shared__ __align__(16) u16 S[3 * 24576];
  int bid = blockIdx.x;                 // 992 m-tiles
  int b  = bid / 31;
  int st = bid - b * 31;
  int sbase = st * 128;
  size_t pixbase = (size_t)b * 4096 + sbase;
  int tid = threadIdx.x, wid = tid >> 6, lane = tid & 63;
  int wm = wid >> 2, wn = wid & 3;

  f32x4 zero = {0.f, 0.f, 0.f, 0.f};
  f32x4 acc[4][4];
#pragma unroll
  for (int ni = 0; ni < 4; ni++)
#pragma unroll
    for (int mi = 0; mi < 4; mi++) acc[ni][mi] = zero;

  int l3 = lane >> 3, l7 = lane & 7;
  int c8x = l7 ^ l3;                       // pre-swizzled source chunk
  int laneA = l3 * 128 + c8x * 8;
  int laneB = l3 * 1152 + c8x * 8;
  int xo = l7 << 4;                        // fragment-read XOR term

  auto stage = [&](int buf, int kt) {      // 6 loads per wave (2 A + 4 B)
    int seg = kt >> 1;
    int chalf = (kt & 1) * 64;
    int dpix = (seg / 3) * 64 + (seg % 3);
    const u16* gA = hp + (pixbase + dpix) * 128 + chalf + laneA;
    const u16* gB = wt + seg * 128 + chalf + laneB;
    u16* Sb = &S[buf * 24576];
#pragma unroll
    for (int i = 0; i < 2; i++) {
      int rb = wid * 16 + i * 8;
      async16(Sb + rb * 64, gA + rb * 128);
    }
#pragma unroll
    for (int i = 0; i < 4; i++) {
      int rb = wid * 32 + i * 8;
      async16(Sb + 8192 + rb * 64, gB + (size_t)rb * 1152);
    }
  };

  stage(0, 0);
  stage(1, 1);

  for (int kt = 0; kt < 18; ++kt) {
    if (kt < 17) asm volatile("s_waitcnt vmcnt(6)" ::: "memory");  // tile kt landed; kt+1 in flight
    else         asm volatile("s_waitcnt vmcnt(0)" ::: "memory");
    __builtin_amdgcn_s_barrier();          // cross-wave: whole tile visible
    asm volatile("" ::: "memory");         // no LDS reads hoist above barrier
    if (kt + 2 < 18) stage((kt + 2) % 3, kt + 2);   // overwrites buf of kt-1 (done)
    const char* Ab = (const char*)&S[(kt % 3) * 24576];
    const char* Bb = Ab + 16384;
#pragma unroll
    for (int kk = 0; kk < 2; kk++) {
      int ko = kk * 64 + ((lane >> 4) * 16);
      bf16x8 af[4], hf[4];
#pragma unroll
      for (int ni = 0; ni < 4; ni++) {
        int row = wn * 64 + ni * 16 + (lane & 15);
        af[ni] = *(const bf16x8*)(Bb + row * 128 + (ko ^ xo));
      }
#pragma unroll
      for (int mi = 0; mi < 4; mi++) {
        int row = wm * 64 + mi * 16 + (lane & 15);
        hf[mi] = *(const bf16x8*)(Ab + row * 128 + (ko ^ xo));
      }
#pragma unroll
      for (int ni = 0; ni < 4; ni++)
#pragma unroll
        for (int mi = 0; mi < 4; mi++)
          acc[ni][mi] = __builtin_amdgcn_mfma_f32_16x16x32_bf16(af[ni], hf[mi], acc[ni][mi], 0, 0, 0);
    }
  }

  // epilogue: D row = n-local quad, col = m; mask junk ow, add residual, store
  int nbase = wn * 64 + ((lane >> 4) << 2);
  int l15 = lane & 15;
#pragma unroll
  for (int mi = 0; mi < 4; mi++) {
    int sl = sbase + wm * 64 + mi * 16 + l15;
    int ow = sl & 63, oh = sl >> 6;
    if (ow >= 62) continue;
#pragma unroll
    for (int ni = 0; ni < 4; ni++) {
      int n0 = nbase + ni * 16;
#pragma unroll
      for (int r = 0; r < 4; r++) {
        int n = n0 + r;
        float v = acc[ni][mi][r];
        if (n < 128) v += x[(size_t)(b * 128 + n) * 4096 + (oh + 1) * 64 + ow + 1];
        out[((size_t)(b * 256 + n) * 62 + oh) * 62 + ow] = v;
      }
    }
  }
}

extern "C" void kernel_launch(void* const* d_in, const int* in_sizes, int n_in,
                              void* d_out, int out_size, void* d_ws, size_t ws_size,
                              hipStream_t stream) {
  const float* x     = (const float*)d_in[0];
  const float* gamma = (const float*)d_in[1];
  const float* beta  = (const float*)d_in[2];
  const float* w     = (const float*)d_in[3];
  float* out = (float*)d_out;
  char* ws = (char*)d_ws;

  const size_t HP_BYTES = (size_t)16777216 * 2 + 4096;  // hp + overrun pad
  u16* hp    = (u16*)ws;
  u16* wt    = (u16*)(ws + HP_BYTES);
  float* part = (float*)(ws + HP_BYTES + 589824);       // 128*4*2 floats

  hipLaunchKernelGGL(statswt_kernel, dim3(512), dim3(256), 0, stream, x, w, part, wt);
  hipLaunchKernelGGL(norm_kernel, dim3(4096), dim3(256), 0, stream, x, gamma, beta, part, hp);
  hipLaunchKernelGGL(conv_kernel, dim3(992), dim3(512), 0, stream, hp, wt, x, out);
}